// Round 5
// baseline (40.773 us; speedup 1.0000x reference)
//
#include <hip/hip_runtime.h>
#include <math.h>

// Problem constants (match reference)
#define BATCH 4
#define LSEQ  4096
#define DCH   512
#define NST   16
#define TCH   32                 // chunk length along L (32 -> 4 waves/SIMD)
#define LOG2_TCH 5
#define CCH   (LSEQ / TCH)       // 128 chunks

// ---------------------------------------------------------------------------
// Kernel 1: per-(b,d,chunk) local scan with h0 = 0; write final chunk state.
// Thread id = (b*CCH + c)*DCH + d  (d fastest -> coalesced x reads).
// states layout: [b][c][n][d] -> state stores lane-coalesced per n.
// ---------------------------------------------------------------------------
__global__ __launch_bounds__(256, 4) void k_local_scan(
    const float* __restrict__ x, const float* __restrict__ A,
    const float* __restrict__ Bm, const float* __restrict__ delta,
    float* __restrict__ states)
{
    int id = blockIdx.x * 256 + threadIdx.x;
    int d  = id % DCH;
    int c  = (id / DCH) % CCH;
    int b  = id / (DCH * CCH);

    float dl = delta[d];
    float dA[NST], dB[NST], h[NST];
#pragma unroll
    for (int n = 0; n < NST; ++n) {
        dA[n] = expf(dl * A[d * NST + n]);
        dB[n] = dl * Bm[d * NST + n];
        h[n]  = 0.f;
    }

    const float* xp = x + ((size_t)b * LSEQ + (size_t)c * TCH) * DCH + d;
#pragma unroll 8
    for (int t = 0; t < TCH; ++t) {
        float xv = xp[(size_t)t * DCH];
#pragma unroll
        for (int n = 0; n < NST; ++n)
            h[n] = fmaf(h[n], dA[n], xv * dB[n]);
    }

#pragma unroll
    for (int n = 0; n < NST; ++n)
        states[(((size_t)b * CCH + c) * NST + n) * DCH + d] = h[n];
}

// ---------------------------------------------------------------------------
// Kernel 2: per-(b,n,d) serial exclusive scan over chunk states, in place.
// d fastest -> coalesced; chunk addresses independent -> unroll pipelines.
// Data is L3-resident (16 MiB).
// ---------------------------------------------------------------------------
__global__ __launch_bounds__(256) void k_chunk_scan(
    const float* __restrict__ A, const float* __restrict__ delta,
    float* __restrict__ states)
{
    int j = blockIdx.x * 256 + threadIdx.x;   // (b, n, d), d fastest
    int d = j % DCH;
    int n = (j / DCH) % NST;
    int b = j / (DCH * NST);

    float dAv = expf(delta[d] * A[d * NST + n]);
    float dAT = dAv;                          // dA^TCH via squarings
#pragma unroll
    for (int k = 0; k < LOG2_TCH; ++k) dAT *= dAT;

    float hp = 0.f;
#pragma unroll 8
    for (int c = 0; c < CCH; ++c) {
        size_t idx = (((size_t)b * CCH + c) * NST + n) * DCH + d;
        float s = states[idx];
        states[idx] = hp;                     // exclusive prefix -> entry state
        hp = fmaf(hp, dAT, s);
    }
}

// ---------------------------------------------------------------------------
// Kernel 3: per-(b,d,chunk) replay from entry state, emit y = sum_n h[n].
// x re-read hits L3 (32 MiB, streamed by K1 moments earlier).
// ---------------------------------------------------------------------------
__global__ __launch_bounds__(256, 4) void k_fixup(
    const float* __restrict__ x, const float* __restrict__ A,
    const float* __restrict__ Bm, const float* __restrict__ delta,
    const float* __restrict__ states, float* __restrict__ y)
{
    int id = blockIdx.x * 256 + threadIdx.x;
    int d  = id % DCH;
    int c  = (id / DCH) % CCH;
    int b  = id / (DCH * CCH);

    float dl = delta[d];
    float dA[NST], dB[NST], h[NST];

#pragma unroll
    for (int n = 0; n < NST; ++n) {
        dA[n] = expf(dl * A[d * NST + n]);
        dB[n] = dl * Bm[d * NST + n];
        h[n]  = states[(((size_t)b * CCH + c) * NST + n) * DCH + d];
    }

    size_t off = ((size_t)b * LSEQ + (size_t)c * TCH) * DCH + d;
    const float* xp = x + off;
    float*       yp = y + off;

#pragma unroll 8
    for (int t = 0; t < TCH; ++t) {
        float xv = xp[(size_t)t * DCH];
#pragma unroll
        for (int n = 0; n < NST; ++n)
            h[n] = fmaf(h[n], dA[n], xv * dB[n]);
        float s01 = (h[0]  + h[1])  + (h[2]  + h[3]);
        float s23 = (h[4]  + h[5])  + (h[6]  + h[7]);
        float s45 = (h[8]  + h[9])  + (h[10] + h[11]);
        float s67 = (h[12] + h[13]) + (h[14] + h[15]);
        yp[(size_t)t * DCH] = (s01 + s23) + (s45 + s67);
    }
}

extern "C" void kernel_launch(void* const* d_in, const int* in_sizes, int n_in,
                              void* d_out, int out_size, void* d_ws, size_t ws_size,
                              hipStream_t stream) {
    const float* x     = (const float*)d_in[0];   // (B, L, D)
    const float* A     = (const float*)d_in[1];   // (D, N)
    const float* Bm    = (const float*)d_in[2];   // (D, N)
    const float* delta = (const float*)d_in[3];   // (D,)
    float*       y     = (float*)d_out;           // (B, L, D)
    float*       states = (float*)d_ws;           // B*C*N*D floats = 16 MiB

    const int n_chunk_threads = BATCH * DCH * CCH;   // 262144
    const int n_state_threads = BATCH * DCH * NST;   // 32768

    k_local_scan<<<n_chunk_threads / 256, 256, 0, stream>>>(x, A, Bm, delta, states);
    k_chunk_scan<<<n_state_threads / 256, 256, 0, stream>>>(A, delta, states);
    k_fixup<<<n_chunk_threads / 256, 256, 0, stream>>>(x, A, Bm, delta, states, y);
}